// Round 1
// baseline (920.075 us; speedup 1.0000x reference)
//
#include <hip/hip_runtime.h>
#include <math.h>

#define HH 64
#define WW 64
#define CIN 256
#define COUT 256
#define BB 4
#define KKT 9
#define HWSZ 4096

// ---------------------------------------------------------------------------
// Kernel 1: transpose w[o][c][kk] (o-major) -> wT[c*9+kk][o] so that the GEMM
// phase reads weights coalesced along o.
// ---------------------------------------------------------------------------
__global__ __launch_bounds__(256) void k_transpose_w(const float* __restrict__ w,
                                                     float* __restrict__ wT) {
    int ck = blockIdx.x;            // 0..2303
    int o  = threadIdx.x;           // 0..255
    wT[(size_t)ck * COUT + o] = w[(size_t)o * 2304 + ck];
}

// ---------------------------------------------------------------------------
// Kernel 2: offset/mask conv. om[b][ch][h][w], ch in 0..26.
// One block per (b,h). 512 threads = 8 c-groups x 64 w-lanes.
// Halo along w handled with wave shuffles (wave=64 == row width).
// ---------------------------------------------------------------------------
__global__ __launch_bounds__(512) void k_off_conv(const float* __restrict__ x,
                                                  const float* __restrict__ w_off,
                                                  const float* __restrict__ b_off,
                                                  float* __restrict__ om) {
    int bh  = blockIdx.x;           // 0..255
    int b   = bh >> 6;
    int h   = bh & 63;
    int tid = threadIdx.x;
    int w   = tid & 63;             // == lane id within wave
    int grp = tid >> 6;             // 0..7 (c-group, wave-uniform)

    float acc[27];
#pragma unroll
    for (int i = 0; i < 27; i++) acc[i] = 0.f;

    const float* xb = x + (size_t)b * CIN * HWSZ;

    for (int ci = 0; ci < 32; ci++) {
        int c = grp * 32 + ci;
        float r[3], l[3], rr[3];
#pragma unroll
        for (int ky = 0; ky < 3; ky++) {
            int yy = h + ky - 1;
            float v = (yy >= 0 && yy < HH) ? xb[(size_t)c * HWSZ + yy * WW + w] : 0.f;
            r[ky] = v;
            float lv = __shfl_up(v, 1);
            l[ky] = (w == 0) ? 0.f : lv;
            float rv = __shfl_down(v, 1);
            rr[ky] = (w == 63) ? 0.f : rv;
        }
        const float* wo = w_off + (size_t)c * 9;
#pragma unroll
        for (int ch = 0; ch < 27; ch++) {
            const float* p = wo + (size_t)ch * (256 * 9);
            acc[ch] += l[0]*p[0] + r[0]*p[1] + rr[0]*p[2]
                     + l[1]*p[3] + r[1]*p[4] + rr[1]*p[5]
                     + l[2]*p[6] + r[2]*p[7] + rr[2]*p[8];
        }
    }

    __shared__ float s_red[8][27][64];
#pragma unroll
    for (int ch = 0; ch < 27; ch++) s_red[grp][ch][w] = acc[ch];
    __syncthreads();

    for (int idx = tid; idx < 27 * 64; idx += 512) {
        int ch = idx >> 6;
        int ww = idx & 63;
        float s = b_off[ch];
#pragma unroll
        for (int g = 0; g < 8; g++) s += s_red[g][ch][ww];
        om[((size_t)b * 27 + ch) * HWSZ + h * WW + ww] = s;
    }
}

// ---------------------------------------------------------------------------
// Kernel 3: fused bilinear sampling + contraction over (c, kk).
// Block = 32 pixels (half row) x all 256 output channels; 256 threads.
// Per c-chunk of 8: stage v[8][9][32] into LDS, then each thread does an
// 8(o) x 4(p) register microtile.
// ---------------------------------------------------------------------------
__global__ __launch_bounds__(256) void k_main(const float* __restrict__ x,
                                              const float* __restrict__ om,
                                              const float* __restrict__ wT,
                                              float* __restrict__ out) {
    int tile = blockIdx.x;          // 0..127
    int b    = blockIdx.y;          // 0..3
    int h    = tile >> 1;
    int w0   = (tile & 1) << 5;     // 0 or 32
    int tid  = threadIdx.x;

    __shared__ int   s_y0[KKT][32];
    __shared__ int   s_x0[KKT][32];
    __shared__ float s_ly[KKT][32];
    __shared__ float s_lx[KKT][32];
    __shared__ float s_m [KKT][32];
    __shared__ float s_v [8 * KKT * 32];

    // ---- Phase A: sampling parameters for the 9*32 (kk, pixel) pairs ----
    const float* omb = om + (size_t)b * 27 * HWSZ + h * WW + w0;
    for (int idx = tid; idx < 288; idx += 256) {
        int kk = idx >> 5;
        int p  = idx & 31;
        float offy = omb[(size_t)(2 * kk)     * HWSZ + p];
        float offx = omb[(size_t)(2 * kk + 1) * HWSZ + p];
        float mv   = omb[(size_t)(18 + kk)    * HWSZ + p];
        int ky = kk / 3, kx = kk % 3;
        float py = (float)(h - 1 + ky) + offy;
        float px = (float)(w0 + p - 1 + kx) + offx;
        float y0f = floorf(py);
        float x0f = floorf(px);
        s_y0[kk][p] = (int)y0f;
        s_x0[kk][p] = (int)x0f;
        s_ly[kk][p] = py - y0f;
        s_lx[kk][p] = px - x0f;
        s_m [kk][p] = 1.f / (1.f + __expf(-mv));
    }

    float4 acc[8];
#pragma unroll
    for (int i = 0; i < 8; i++) acc[i] = make_float4(0.f, 0.f, 0.f, 0.f);
    int og = tid >> 3;              // 0..31 -> o base = og*8
    int pg = tid & 7;               // 0..7  -> pixels pg*4..pg*4+3
    const float* xb = x + (size_t)b * CIN * HWSZ;

    for (int c0 = 0; c0 < CIN; c0 += 8) {
        __syncthreads();            // also covers Phase A on first iteration

        // ---- stage v[8][9][32] ----
#pragma unroll
        for (int it = 0; it < 9; it++) {
            int s   = it * 256 + tid;      // 0..2303
            int c   = s / 288;
            int rem = s - c * 288;
            int kk  = rem >> 5;
            int p   = rem & 31;
            const float* xc = xb + (size_t)(c0 + c) * HWSZ;
            int   y0 = s_y0[kk][p];
            int   x0 = s_x0[kk][p];
            float ly = s_ly[kk][p];
            float lx = s_lx[kk][p];
            bool yv0 = (unsigned)y0       < HH;
            bool yv1 = (unsigned)(y0 + 1) < HH;
            bool xv0 = (unsigned)x0       < WW;
            bool xv1 = (unsigned)(x0 + 1) < WW;
            float v00 = (yv0 && xv0) ? xc[y0 * WW + x0]           : 0.f;
            float v01 = (yv0 && xv1) ? xc[y0 * WW + x0 + 1]       : 0.f;
            float v10 = (yv1 && xv0) ? xc[(y0 + 1) * WW + x0]     : 0.f;
            float v11 = (yv1 && xv1) ? xc[(y0 + 1) * WW + x0 + 1] : 0.f;
            float val = (v00 * (1.f - ly) * (1.f - lx)
                       + v01 * (1.f - ly) * lx
                       + v10 * ly * (1.f - lx)
                       + v11 * ly * lx) * s_m[kk][p];
            s_v[(c * KKT + kk) * 32 + p] = val;
        }
        __syncthreads();

        // ---- register-tiled FMA over the 72 (c,kk) rows of this chunk ----
        const float* wp = wT + (size_t)c0 * KKT * COUT + og * 8;
#pragma unroll 8
        for (int ck = 0; ck < 72; ck++) {
            float4 v4 = *(const float4*)&s_v[ck * 32 + pg * 4];
            float4 wa = *(const float4*)(wp + (size_t)ck * COUT);
            float4 wb = *(const float4*)(wp + (size_t)ck * COUT + 4);
            float wv[8] = {wa.x, wa.y, wa.z, wa.w, wb.x, wb.y, wb.z, wb.w};
#pragma unroll
            for (int i = 0; i < 8; i++) {
                acc[i].x += wv[i] * v4.x;
                acc[i].y += wv[i] * v4.y;
                acc[i].z += wv[i] * v4.z;
                acc[i].w += wv[i] * v4.w;
            }
        }
    }

    // ---- store 8 o-rows x 4 pixels ----
    float* op = out + ((size_t)b * COUT + og * 8) * HWSZ + h * WW + w0 + pg * 4;
#pragma unroll
    for (int i = 0; i < 8; i++) {
        *(float4*)(op + (size_t)i * HWSZ) = acc[i];
    }
}

extern "C" void kernel_launch(void* const* d_in, const int* in_sizes, int n_in,
                              void* d_out, int out_size, void* d_ws, size_t ws_size,
                              hipStream_t stream) {
    const float* x     = (const float*)d_in[0];
    const float* w_off = (const float*)d_in[1];
    const float* b_off = (const float*)d_in[2];
    const float* w     = (const float*)d_in[3];
    float* out = (float*)d_out;

    float* om = (float*)d_ws;                  // 4*27*4096   = 442368 floats
    float* wT = om + 442368;                   // 2304*256    = 589824 floats

    hipLaunchKernelGGL(k_transpose_w, dim3(2304), dim3(256), 0, stream, w, wT);
    hipLaunchKernelGGL(k_off_conv, dim3(256), dim3(512), 0, stream, x, w_off, b_off, om);
    hipLaunchKernelGGL(k_main, dim3(128, 4), dim3(256), 0, stream, x, om, wT, out);
}

// Round 2
// 411.414 us; speedup vs baseline: 2.2364x; 2.2364x over previous
//
#include <hip/hip_runtime.h>
#include <math.h>

#define HH 64
#define WW 64
#define CIN 256
#define COUT 256
#define KKT 9
#define HWSZ 4096
#define NCHUNK 72              // 2304 / 32 K-chunks; k' = kk*256 + c

typedef __bf16  v8bf   __attribute__((ext_vector_type(8)));
typedef float   v4f    __attribute__((ext_vector_type(4)));
typedef short   short8 __attribute__((ext_vector_type(8)));

__device__ inline unsigned short f2bf(float f) {   // round-to-nearest-even
    union { float f; unsigned u; } uf; uf.f = f;
    unsigned r = uf.u + 0x7fff + ((uf.u >> 16) & 1);
    return (unsigned short)(r >> 16);
}

// ---------------------------------------------------------------------------
// Kernel 1: prep W. w[o][c][kk] fp32 -> wprep bf16 in chunked layout:
//   k' = kk*256 + c, chunk t = k'>>5, ki = k'&31
//   wprep[(t*256 + o)*32 + ki]
// Coalesced reads (thread=ck), scattered 2B writes (L2-absorbed).
// ---------------------------------------------------------------------------
__global__ __launch_bounds__(256) void k_prep_w(const float* __restrict__ w,
                                                unsigned short* __restrict__ wprep) {
    int o = blockIdx.x;
    for (int ck = threadIdx.x; ck < 2304; ck += 256) {
        float v = w[(size_t)o * 2304 + ck];
        int c  = ck / 9;
        int kk = ck - 9 * c;
        int kp = kk * 256 + c;
        int t  = kp >> 5;
        int ki = kp & 31;
        wprep[((size_t)(t * 256 + o)) * 32 + ki] = f2bf(v);
    }
}

// ---------------------------------------------------------------------------
// Kernel 2: offset/mask conv (unchanged from R1 — correct, ~est 20-40us).
// ---------------------------------------------------------------------------
__global__ __launch_bounds__(512) void k_off_conv(const float* __restrict__ x,
                                                  const float* __restrict__ w_off,
                                                  const float* __restrict__ b_off,
                                                  float* __restrict__ om) {
    int bh  = blockIdx.x;
    int b   = bh >> 6;
    int h   = bh & 63;
    int tid = threadIdx.x;
    int w   = tid & 63;
    int grp = tid >> 6;

    float acc[27];
#pragma unroll
    for (int i = 0; i < 27; i++) acc[i] = 0.f;

    const float* xb = x + (size_t)b * CIN * HWSZ;

    for (int ci = 0; ci < 32; ci++) {
        int c = grp * 32 + ci;
        float r[3], l[3], rr[3];
#pragma unroll
        for (int ky = 0; ky < 3; ky++) {
            int yy = h + ky - 1;
            float v = (yy >= 0 && yy < HH) ? xb[(size_t)c * HWSZ + yy * WW + w] : 0.f;
            r[ky] = v;
            float lv = __shfl_up(v, 1);
            l[ky] = (w == 0) ? 0.f : lv;
            float rv = __shfl_down(v, 1);
            rr[ky] = (w == 63) ? 0.f : rv;
        }
        const float* wo = w_off + (size_t)c * 9;
#pragma unroll
        for (int ch = 0; ch < 27; ch++) {
            const float* p = wo + (size_t)ch * (256 * 9);
            acc[ch] += l[0]*p[0] + r[0]*p[1] + rr[0]*p[2]
                     + l[1]*p[3] + r[1]*p[4] + rr[1]*p[5]
                     + l[2]*p[6] + r[2]*p[7] + rr[2]*p[8];
        }
    }

    __shared__ float s_red[8][27][64];
#pragma unroll
    for (int ch = 0; ch < 27; ch++) s_red[grp][ch][w] = acc[ch];
    __syncthreads();

    for (int idx = tid; idx < 27 * 64; idx += 512) {
        int ch = idx >> 6;
        int ww = idx & 63;
        float s = b_off[ch];
#pragma unroll
        for (int g = 0; g < 8; g++) s += s_red[g][ch][ww];
        om[((size_t)b * 27 + ch) * HWSZ + h * WW + ww] = s;
    }
}

// ---------------------------------------------------------------------------
// Kernel 3: fused sampling + bf16 MFMA GEMM.
// Block: 256 thr (4 waves), tile 128 Cout x 64 px (one (b,h) row).
// grid (256 ptiles, 2 o-halves) = 512 blocks (2/CU).
// K permuted as k' = kk*256 + c: every 32-chunk shares one kk, so bilinear
// params load once per chunk and amortize over 8 channel samples.
// ---------------------------------------------------------------------------
__global__ __launch_bounds__(256) void k_main(const float* __restrict__ x,
                                              const float* __restrict__ om,
                                              const unsigned short* __restrict__ wprep,
                                              float* __restrict__ out) {
    const int pt    = blockIdx.x;      // 0..255 : (b,h)
    const int ohalf = blockIdx.y;      // 0..1
    const int b     = pt >> 6;
    const int h     = pt & 63;
    const int tid   = threadIdx.x;
    const int lane  = tid & 63;        // pixel p (= w coordinate)
    const int oct   = tid >> 6;        // wave id; also channel-octet selector

    __shared__ int4   s_idx[KKT][64];          // clamped gather indices
    __shared__ float4 s_wt [KKT][64];          // bilinear*valid*mask weights
    __shared__ unsigned short s_w[128 * 40];   // W tile [o][k], row pad->40
    __shared__ unsigned short s_v[64 * 40];    // V tile [p][k], row pad->40

    // ---- Phase A: per-(kk,pixel) sampling parameters ----
    const float* omb = om + (size_t)b * 27 * HWSZ + h * WW;
    for (int i = tid; i < KKT * 64; i += 256) {
        int kk = i >> 6;
        int p  = i & 63;
        float offy = omb[(size_t)(2 * kk)     * HWSZ + p];
        float offx = omb[(size_t)(2 * kk + 1) * HWSZ + p];
        float mv   = omb[(size_t)(18 + kk)    * HWSZ + p];
        int ky = kk / 3, kx = kk - 3 * (kk / 3);
        float py = (float)(h - 1 + ky) + offy;
        float px = (float)(p - 1 + kx) + offx;
        float y0f = floorf(py);
        float x0f = floorf(px);
        float ly = py - y0f;
        float lx = px - x0f;
        int y0 = (int)y0f;
        int x0 = (int)x0f;
        float m = 1.f / (1.f + __expf(-mv));
        bool yv0 = (unsigned)y0       < HH;
        bool yv1 = (unsigned)(y0 + 1) < HH;
        bool xv0 = (unsigned)x0       < WW;
        bool xv1 = (unsigned)(x0 + 1) < WW;
        int y0c = min(max(y0, 0), HH - 1);
        int y1c = min(max(y0 + 1, 0), HH - 1);
        int x0c = min(max(x0, 0), WW - 1);
        int x1c = min(max(x0 + 1, 0), WW - 1);
        s_idx[kk][p] = make_int4(y0c * WW + x0c, y0c * WW + x1c,
                                 y1c * WW + x0c, y1c * WW + x1c);
        s_wt[kk][p] = make_float4(
            (yv0 && xv0) ? (1.f - ly) * (1.f - lx) * m : 0.f,
            (yv0 && xv1) ? (1.f - ly) * lx         * m : 0.f,
            (yv1 && xv0) ? ly * (1.f - lx)         * m : 0.f,
            (yv1 && xv1) ? ly * lx                 * m : 0.f);
    }
    __syncthreads();

    v4f acc[4][2];
#pragma unroll
    for (int mt = 0; mt < 4; mt++)
#pragma unroll
        for (int nt = 0; nt < 2; nt++) acc[mt][nt] = (v4f)(0.f);

    const int m16   = lane & 15;
    const int quad  = lane >> 4;
    const int mhalf = oct & 1;
    const int nhalf = oct >> 1;
    const float* xb = x + (size_t)b * CIN * HWSZ;

    for (int t = 0; t < NCHUNK; t++) {
        const int kk  = t >> 3;                      // shared by whole chunk
        const int c0c = ((t & 7) << 5) + oct * 8;    // this thread's 8 channels

        // ---- stage W[128][32] for this chunk (2 x 16B per thread) ----
        const unsigned short* wp = wprep + ((size_t)(t * 256 + ohalf * 128)) * 32;
#pragma unroll
        for (int i = 0; i < 2; i++) {
            int u = i * 256 + tid;                   // 0..511 16B-units
            int o = u >> 2, kq = u & 3;
            *(short8*)&s_w[o * 40 + kq * 8] = *(const short8*)(wp + u * 8);
        }

        // ---- sample 8 channels at (kk, lane) -> V[lane][oct*8 .. +7] ----
        int4   id4 = s_idx[kk][lane];
        float4 wt4 = s_wt[kk][lane];
        const float* xc = xb + (size_t)c0c * HWSZ;
        unsigned short vv[8];
#pragma unroll
        for (int j = 0; j < 8; j++) {
            const float* xp = xc + (size_t)j * HWSZ;
            float val = wt4.x * xp[id4.x] + wt4.y * xp[id4.y]
                      + wt4.z * xp[id4.z] + wt4.w * xp[id4.w];
            vv[j] = f2bf(val);
        }
        *(short8*)&s_v[lane * 40 + oct * 8] = *(short8*)vv;

        __syncthreads();

        // ---- MFMA: wave computes 64o x 32p of the 128x64 tile ----
        short8 af[4], bfr[2];
#pragma unroll
        for (int mt = 0; mt < 4; mt++)
            af[mt] = *(const short8*)&s_w[(mhalf * 64 + mt * 16 + m16) * 40 + quad * 8];
#pragma unroll
        for (int nt = 0; nt < 2; nt++)
            bfr[nt] = *(const short8*)&s_v[(nhalf * 32 + nt * 16 + m16) * 40 + quad * 8];
#pragma unroll
        for (int mt = 0; mt < 4; mt++)
#pragma unroll
            for (int nt = 0; nt < 2; nt++)
                acc[mt][nt] = __builtin_amdgcn_mfma_f32_16x16x32_bf16(
                    __builtin_bit_cast(v8bf, af[mt]),
                    __builtin_bit_cast(v8bf, bfr[nt]),
                    acc[mt][nt], 0, 0, 0);

        __syncthreads();
    }

    // ---- epilogue: C/D layout col=lane&15 (p), row=quad*4+r (o) ----
    float* ob = out + ((size_t)b * COUT) * HWSZ + h * WW;
#pragma unroll
    for (int mt = 0; mt < 4; mt++) {
#pragma unroll
        for (int nt = 0; nt < 2; nt++) {
#pragma unroll
            for (int r = 0; r < 4; r++) {
                int o = ohalf * 128 + mhalf * 64 + mt * 16 + quad * 4 + r;
                int p = nhalf * 32 + nt * 16 + m16;
                ob[(size_t)o * HWSZ + p] = acc[mt][nt][r];
            }
        }
    }
}

extern "C" void kernel_launch(void* const* d_in, const int* in_sizes, int n_in,
                              void* d_out, int out_size, void* d_ws, size_t ws_size,
                              hipStream_t stream) {
    const float* x     = (const float*)d_in[0];
    const float* w_off = (const float*)d_in[1];
    const float* b_off = (const float*)d_in[2];
    const float* w     = (const float*)d_in[3];
    float* out = (float*)d_out;

    float* om = (float*)d_ws;                         // 4*27*4096 floats
    unsigned short* wprep = (unsigned short*)(om + 442368);  // 2304*256 bf16

    hipLaunchKernelGGL(k_prep_w, dim3(256), dim3(256), 0, stream, w, wprep);
    hipLaunchKernelGGL(k_off_conv, dim3(256), dim3(512), 0, stream, x, w_off, b_off, om);
    hipLaunchKernelGGL(k_main, dim3(256, 2), dim3(256), 0, stream, x, om, wprep, out);
}

// Round 3
// 230.798 us; speedup vs baseline: 3.9865x; 1.7826x over previous
//
#include <hip/hip_runtime.h>
#include <math.h>

#define HH 64
#define WW 64
#define CIN 256
#define COUT 256
#define KKT 9
#define HWSZ 4096
#define NCHUNK 72              // 2304/32 K-chunks; permuted k' = kk*256 + c
#define VPAD 34                // s_v row pitch (shorts) — conflict-free b128

typedef __bf16  v8bf   __attribute__((ext_vector_type(8)));
typedef float   v4f    __attribute__((ext_vector_type(4)));
typedef short   short8 __attribute__((ext_vector_type(8)));
typedef unsigned short ushort4v __attribute__((ext_vector_type(4)));

__device__ inline unsigned short f2bf(float f) {   // RNE
    union { float f; unsigned u; } uf; uf.f = f;
    unsigned r = uf.u + 0x7fff + ((uf.u >> 16) & 1);
    return (unsigned short)(r >> 16);
}
__device__ inline float bf2f(unsigned short u) {
    union { unsigned u; float f; } uf; uf.u = ((unsigned)u) << 16;
    return uf.f;
}

// ---------------------------------------------------------------------------
// Prep 1: x[b][c][h][w] f32 -> x_t[b][h][w][c] bf16 (channel-last).
// One block per (b,h). Coalesced reads; 16B channel-packed writes.
// ---------------------------------------------------------------------------
__global__ __launch_bounds__(256) void k_prep_x(const float* __restrict__ x,
                                                unsigned short* __restrict__ x_t) {
    int bh = blockIdx.x;
    int b  = bh >> 6;
    int h  = bh & 63;
    int px  = threadIdx.x & 63;
    int oct = threadIdx.x >> 6;            // 0..3
    const float* xr = x + (((size_t)b * CIN) * HH + h) * WW;
    unsigned short* orow = x_t + (((size_t)bh) * WW + px) * CIN;
    for (int g = 0; g < 8; g++) {
        int cb = g * 32 + oct * 8;
        unsigned short v[8];
#pragma unroll
        for (int j = 0; j < 8; j++)
            v[j] = f2bf(xr[(size_t)(cb + j) * HWSZ + px]);
        *(short8*)(orow + cb) = *(short8*)v;
    }
}

// ---------------------------------------------------------------------------
// Prep 2: w[o][c][kk] f32 -> wprep bf16, chunked: wprep[(t*256+o)*32 + ki],
// t = (kk*256+c)>>5, ki = (kk*256+c)&31.
// ---------------------------------------------------------------------------
__global__ __launch_bounds__(256) void k_prep_w(const float* __restrict__ w,
                                                unsigned short* __restrict__ wprep) {
    int o = blockIdx.x;
    for (int ck = threadIdx.x; ck < 2304; ck += 256) {
        float v = w[(size_t)o * 2304 + ck];
        int c  = ck / 9;
        int kk = ck - 9 * c;
        int kp = kk * 256 + c;
        wprep[((size_t)((kp >> 5) * 256 + o)) * 32 + (kp & 31)] = f2bf(v);
    }
}

// ---------------------------------------------------------------------------
// Prep 3: w_off[27][c][kk] -> woffp[t][32(och,pad0)][32(ki)] bf16.
// ---------------------------------------------------------------------------
__global__ __launch_bounds__(256) void k_prep_woff(const float* __restrict__ w_off,
                                                   unsigned short* __restrict__ woffp) {
    int t = blockIdx.x;                    // 0..71
#pragma unroll
    for (int i = 0; i < 4; i++) {
        int idx = i * 256 + threadIdx.x;   // 0..1023
        int och = idx >> 5;
        int ki  = idx & 31;
        int kp  = t * 32 + ki;
        int kk  = kp >> 8;
        int c   = kp & 255;
        float v = (och < 27) ? w_off[((size_t)och * 256 + c) * 9 + kk] : 0.f;
        woffp[(size_t)t * 1024 + idx] = f2bf(v);
    }
}

// ---------------------------------------------------------------------------
// Offset conv as MFMA GEMM: om[b][27][h][w] (fp32), M=32 N=64(px) K=2304.
// One block per (b,h), 256 thr (4 waves). im2col tap = direct 16B x_t load.
// ---------------------------------------------------------------------------
__global__ __launch_bounds__(256) void k_off_mfma(const unsigned short* __restrict__ x_t,
                                                  const unsigned short* __restrict__ woffp,
                                                  const float* __restrict__ b_off,
                                                  float* __restrict__ om) {
    int id = blockIdx.x;
    int g  = id & 7, hi = (id >> 3) & 7, b = id >> 6;
    int h  = g * 8 + hi;
    int tid  = threadIdx.x;
    int lane = tid & 63;
    int wv   = tid >> 6;                   // wave id = n-tile
    int m16  = lane & 15;
    int quad = lane >> 4;

    __shared__ unsigned short s_v[64 * VPAD];

    v4f acc[2];
    acc[0] = (v4f)(0.f);
    acc[1] = (v4f)(0.f);

    const unsigned short* xb = x_t + (size_t)b * HWSZ * CIN;

    for (int t = 0; t < NCHUNK; t++) {
        int kk = t >> 3;
        int c0 = (t & 7) << 5;
        int ky = kk / 3 - 1, kx = kk - 3 * (kk / 3) - 1;

        // stage V[64px][32ch]: thread: px=lane, ch-oct=wv*8
        {
            int y = h + ky;
            int xc = lane + kx;
            short8 val = (short8)0;
            if ((unsigned)y < HH && (unsigned)xc < WW)
                val = *(const short8*)(xb + ((size_t)y * WW + xc) * CIN + c0 + wv * 8);
            *(short8*)&s_v[lane * VPAD + wv * 8] = val;
        }
        __syncthreads();

        const unsigned short* wp = woffp + (size_t)t * 1024;
        short8 af0 = *(const short8*)(wp + m16 * 32 + quad * 8);
        short8 af1 = *(const short8*)(wp + (16 + m16) * 32 + quad * 8);
        short8 bfr = *(const short8*)&s_v[(wv * 16 + m16) * VPAD + quad * 8];

        acc[0] = __builtin_amdgcn_mfma_f32_16x16x32_bf16(
            __builtin_bit_cast(v8bf, af0), __builtin_bit_cast(v8bf, bfr), acc[0], 0, 0, 0);
        acc[1] = __builtin_amdgcn_mfma_f32_16x16x32_bf16(
            __builtin_bit_cast(v8bf, af1), __builtin_bit_cast(v8bf, bfr), acc[1], 0, 0, 0);
        __syncthreads();
    }

    // epilogue: D col=px(lane&15), row=quad*4+r
#pragma unroll
    for (int mt = 0; mt < 2; mt++) {
#pragma unroll
        for (int r = 0; r < 4; r++) {
            int och = mt * 16 + quad * 4 + r;
            if (och < 27)
                om[((size_t)b * 27 + och) * HWSZ + h * WW + wv * 16 + m16] =
                    acc[mt][r] + b_off[och];
        }
    }
}

// ---------------------------------------------------------------------------
// Main: fused sampling + bf16 MFMA GEMM. One block per (b,h) row, 512 thr
// (8 waves). Tile 256o x 64px. Wave w: o in [w*32, w*32+32). W A-frags read
// directly from global (L2-resident). V staged in LDS (sampled once).
// ---------------------------------------------------------------------------
__global__ __launch_bounds__(512) void k_main(const unsigned short* __restrict__ x_t,
                                              const float* __restrict__ om,
                                              const unsigned short* __restrict__ wprep,
                                              float* __restrict__ out) {
    int id = blockIdx.x;
    int g  = id & 7, hi = (id >> 3) & 7, b = id >> 6;
    int h  = g * 8 + hi;
    int tid  = threadIdx.x;
    int lane = tid & 63;
    int oct  = tid >> 6;                   // 0..7 wave id
    int m16  = lane & 15;
    int quad = lane >> 4;

    __shared__ int   s_base[KKT][64][4];   // tap element-offset (y*64+x)*256
    __shared__ float s_wt  [KKT][64][4];   // bilinear*valid*mask weights
    __shared__ unsigned short s_v[64 * VPAD];

    // ---- Phase A: sampling params per (kk, px) ----
    const float* omb = om + (size_t)b * 27 * HWSZ + h * WW;
    for (int i = tid; i < KKT * 64; i += 512) {
        int kk = i >> 6;
        int p  = i & 63;
        float offy = omb[(size_t)(2 * kk)     * HWSZ + p];
        float offx = omb[(size_t)(2 * kk + 1) * HWSZ + p];
        float mv   = omb[(size_t)(18 + kk)    * HWSZ + p];
        int ky = kk / 3, kx = kk - 3 * (kk / 3);
        float py = (float)(h - 1 + ky) + offy;
        float px = (float)(p - 1 + kx) + offx;
        float y0f = floorf(py);
        float x0f = floorf(px);
        float ly = py - y0f, lx = px - x0f;
        int y0 = (int)y0f, x0 = (int)x0f;
        float m = 1.f / (1.f + __expf(-mv));
        bool yv0 = (unsigned)y0       < HH;
        bool yv1 = (unsigned)(y0 + 1) < HH;
        bool xv0 = (unsigned)x0       < WW;
        bool xv1 = (unsigned)(x0 + 1) < WW;
        int y0c = min(max(y0, 0), HH - 1);
        int y1c = min(max(y0 + 1, 0), HH - 1);
        int x0c = min(max(x0, 0), WW - 1);
        int x1c = min(max(x0 + 1, 0), WW - 1);
        s_base[kk][p][0] = (y0c * WW + x0c) * CIN;
        s_base[kk][p][1] = (y0c * WW + x1c) * CIN;
        s_base[kk][p][2] = (y1c * WW + x0c) * CIN;
        s_base[kk][p][3] = (y1c * WW + x1c) * CIN;
        s_wt[kk][p][0] = (yv0 && xv0) ? (1.f - ly) * (1.f - lx) * m : 0.f;
        s_wt[kk][p][1] = (yv0 && xv1) ? (1.f - ly) * lx         * m : 0.f;
        s_wt[kk][p][2] = (yv1 && xv0) ? ly * (1.f - lx)         * m : 0.f;
        s_wt[kk][p][3] = (yv1 && xv1) ? ly * lx                 * m : 0.f;
    }
    __syncthreads();

    v4f acc[2][4];
#pragma unroll
    for (int mt = 0; mt < 2; mt++)
#pragma unroll
        for (int nt = 0; nt < 4; nt++) acc[mt][nt] = (v4f)(0.f);

    const unsigned short* xb = x_t + (size_t)b * HWSZ * CIN;

    for (int t = 0; t < NCHUNK; t++) {
        int kk = t >> 3;
        int c0 = (t & 7) << 5;

        // W A-frags straight from global (issue early; L2-resident)
        const unsigned short* wp = wprep + ((size_t)t * 256 + oct * 32) * 32;
        short8 af0 = *(const short8*)(wp + m16 * 32 + quad * 8);
        short8 af1 = *(const short8*)(wp + (16 + m16) * 32 + quad * 8);

        // sample 4 channels (c0 + oct*4 ..) at (kk, lane)
        {
            const int*   bp = s_base[kk][lane];
            const float* wt = s_wt[kk][lane];
            const unsigned short* xc = xb + c0 + oct * 4;
            ushort4v t0 = *(const ushort4v*)(xc + bp[0]);
            ushort4v t1 = *(const ushort4v*)(xc + bp[1]);
            ushort4v t2 = *(const ushort4v*)(xc + bp[2]);
            ushort4v t3 = *(const ushort4v*)(xc + bp[3]);
            unsigned short vv[4];
#pragma unroll
            for (int j = 0; j < 4; j++) {
                float val = wt[0] * bf2f(t0[j]) + wt[1] * bf2f(t1[j])
                          + wt[2] * bf2f(t2[j]) + wt[3] * bf2f(t3[j]);
                vv[j] = f2bf(val);
            }
            *(ushort4v*)&s_v[lane * VPAD + oct * 4] = *(ushort4v*)vv;
        }
        __syncthreads();

        short8 bfr[4];
#pragma unroll
        for (int nt = 0; nt < 4; nt++)
            bfr[nt] = *(const short8*)&s_v[(nt * 16 + m16) * VPAD + quad * 8];
#pragma unroll
        for (int nt = 0; nt < 4; nt++) {
            acc[0][nt] = __builtin_amdgcn_mfma_f32_16x16x32_bf16(
                __builtin_bit_cast(v8bf, af0), __builtin_bit_cast(v8bf, bfr[nt]),
                acc[0][nt], 0, 0, 0);
            acc[1][nt] = __builtin_amdgcn_mfma_f32_16x16x32_bf16(
                __builtin_bit_cast(v8bf, af1), __builtin_bit_cast(v8bf, bfr[nt]),
                acc[1][nt], 0, 0, 0);
        }
        __syncthreads();
    }

    // ---- epilogue: o = oct*32 + mt*16 + quad*4 + r, px = nt*16 + m16 ----
    float* ob = out + ((size_t)b * COUT) * HWSZ + h * WW;
#pragma unroll
    for (int mt = 0; mt < 2; mt++)
#pragma unroll
        for (int nt = 0; nt < 4; nt++)
#pragma unroll
            for (int r = 0; r < 4; r++) {
                int o = oct * 32 + mt * 16 + quad * 4 + r;
                ob[(size_t)o * HWSZ + nt * 16 + m16] = acc[mt][nt][r];
            }
}

extern "C" void kernel_launch(void* const* d_in, const int* in_sizes, int n_in,
                              void* d_out, int out_size, void* d_ws, size_t ws_size,
                              hipStream_t stream) {
    const float* x     = (const float*)d_in[0];
    const float* w_off = (const float*)d_in[1];
    const float* b_off = (const float*)d_in[2];
    const float* w     = (const float*)d_in[3];
    float* out = (float*)d_out;

    float* om = (float*)d_ws;                              // 442368 f32
    unsigned short* x_t   = (unsigned short*)(om + 442368);  // 4.19M bf16
    unsigned short* wprep = x_t + (size_t)4 * HWSZ * CIN;    // 589824 bf16
    unsigned short* woffp = wprep + 589824;                  // 73728 bf16

    hipLaunchKernelGGL(k_prep_x,    dim3(256), dim3(256), 0, stream, x, x_t);
    hipLaunchKernelGGL(k_prep_w,    dim3(256), dim3(256), 0, stream, w, wprep);
    hipLaunchKernelGGL(k_prep_woff, dim3(72),  dim3(256), 0, stream, w_off, woffp);
    hipLaunchKernelGGL(k_off_mfma,  dim3(256), dim3(256), 0, stream, x_t, woffp, b_off, om);
    hipLaunchKernelGGL(k_main,      dim3(256), dim3(512), 0, stream, x_t, om, wprep, out);
}

// Round 4
// 156.569 us; speedup vs baseline: 5.8765x; 1.4741x over previous
//
#include <hip/hip_runtime.h>
#include <math.h>

#define HH 64
#define WW 64
#define CIN 256
#define COUT 256
#define KKT 9
#define HWSZ 4096
#define VP 260                 // s_v row pitch in shorts (130 dw == 2 mod 32)

typedef __bf16  v8bf   __attribute__((ext_vector_type(8)));
typedef float   v4f    __attribute__((ext_vector_type(4)));
typedef short   short8 __attribute__((ext_vector_type(8)));
typedef unsigned short ushort4v __attribute__((ext_vector_type(4)));

__device__ inline unsigned short f2bf(float f) {   // RNE
    union { float f; unsigned u; } uf; uf.f = f;
    unsigned r = uf.u + 0x7fff + ((uf.u >> 16) & 1);
    return (unsigned short)(r >> 16);
}
__device__ inline float bf2f(unsigned short u) {
    union { unsigned u; float f; } uf; uf.u = ((unsigned)u) << 16;
    return uf.f;
}

// ---------------------------------------------------------------------------
// Prep 1: x[b][c][h][w] f32 -> x_t[b][h][w][c] bf16 (channel-last).
// ---------------------------------------------------------------------------
__global__ __launch_bounds__(256) void k_prep_x(const float* __restrict__ x,
                                                unsigned short* __restrict__ x_t) {
    int bh = blockIdx.x;
    int b  = bh >> 6;
    int h  = bh & 63;
    int px  = threadIdx.x & 63;
    int oct = threadIdx.x >> 6;
    const float* xr = x + (((size_t)b * CIN) * HH + h) * WW;
    unsigned short* orow = x_t + (((size_t)bh) * WW + px) * CIN;
    for (int g = 0; g < 8; g++) {
        int cb = g * 32 + oct * 8;
        unsigned short v[8];
#pragma unroll
        for (int j = 0; j < 8; j++)
            v[j] = f2bf(xr[(size_t)(cb + j) * HWSZ + px]);
        *(short8*)(orow + cb) = *(short8*)v;
    }
}

// ---------------------------------------------------------------------------
// Prep 2 (merged): blocks 0..255: w -> wprep[(t*256+o)*32+ki] bf16,
// t=(kk*256+c)>>5, ki=(kk*256+c)&31.  blocks 256..327: w_off -> woffp[t][32][32].
// ---------------------------------------------------------------------------
__global__ __launch_bounds__(256) void k_prep_wts(const float* __restrict__ w,
                                                  const float* __restrict__ w_off,
                                                  unsigned short* __restrict__ wprep,
                                                  unsigned short* __restrict__ woffp) {
    if (blockIdx.x < 256) {
        int o = blockIdx.x;
        for (int ck = threadIdx.x; ck < 2304; ck += 256) {
            float v = w[(size_t)o * 2304 + ck];
            int c  = ck / 9;
            int kk = ck - 9 * c;
            int kp = kk * 256 + c;
            wprep[((size_t)((kp >> 5) * 256 + o)) * 32 + (kp & 31)] = f2bf(v);
        }
    } else {
        int t = blockIdx.x - 256;          // 0..71
#pragma unroll
        for (int i = 0; i < 4; i++) {
            int idx = i * 256 + threadIdx.x;
            int och = idx >> 5;
            int ki  = idx & 31;
            int kp  = t * 32 + ki;
            int kk  = kp >> 8;
            int c   = kp & 255;
            float v = (och < 27) ? w_off[((size_t)och * 256 + c) * 9 + kk] : 0.f;
            woffp[(size_t)t * 1024 + idx] = f2bf(v);
        }
    }
}

// ---------------------------------------------------------------------------
// Offset conv as MFMA GEMM, row-staged: per ky stage one full x_t row into
// LDS (coalesced), then 3 kx x 8 chunks x 2 MFMA. 6 barriers total.
// ---------------------------------------------------------------------------
__global__ __launch_bounds__(256) void k_off_mfma(const unsigned short* __restrict__ x_t,
                                                  const unsigned short* __restrict__ woffp,
                                                  const float* __restrict__ b_off,
                                                  float* __restrict__ om) {
    int id = blockIdx.x;
    int g  = id & 7, hi = (id >> 3) & 7, b = id >> 6;
    int h  = g * 8 + hi;
    int tid  = threadIdx.x;
    int lane = tid & 63;
    int wv   = tid >> 6;                   // 0..3, n-tile (16 px each)
    int m16  = lane & 15;
    int quad = lane >> 4;

    __shared__ unsigned short s_row[66 * VP];   // px 0..65 (halo), 34.3 KB

    v4f acc[2];
    acc[0] = (v4f)(0.f);
    acc[1] = (v4f)(0.f);

    const unsigned short* xb = x_t + (size_t)b * HWSZ * CIN;

    // zero the px halo columns once
    if (tid < 64) {
        int hpx = (tid >> 5) * 65;         // 0 or 65
        int c8  = (tid & 31) * 8;
        *(short8*)&s_row[hpx * VP + c8] = (short8)0;
    }

    for (int ky = 0; ky < 3; ky++) {
        int y = h + ky - 1;
        __syncthreads();                   // protect s_row from prior readers
        if ((unsigned)y < HH) {
            const unsigned short* src = xb + (size_t)y * WW * CIN;
#pragma unroll
            for (int i = 0; i < 8; i++) {
                int u  = i * 256 + tid;    // 0..2047
                int px = u >> 5;
                int c8 = (u & 31) * 8;
                *(short8*)&s_row[(px + 1) * VP + c8] = *(const short8*)(src + px * CIN + c8);
            }
        } else {
#pragma unroll
            for (int i = 0; i < 8; i++) {
                int u  = i * 256 + tid;
                int px = u >> 5;
                int c8 = (u & 31) * 8;
                *(short8*)&s_row[(px + 1) * VP + c8] = (short8)0;
            }
        }
        __syncthreads();

#pragma unroll
        for (int kx = 0; kx < 3; kx++) {
            int kk = ky * 3 + kx;
#pragma unroll 4
            for (int ch = 0; ch < 8; ch++) {
                int t = kk * 8 + ch;
                const unsigned short* wp = woffp + (size_t)t * 1024;
                short8 af0 = *(const short8*)(wp + m16 * 32 + quad * 8);
                short8 af1 = *(const short8*)(wp + (16 + m16) * 32 + quad * 8);
                short8 bfr = *(const short8*)&s_row[(wv * 16 + m16 + kx) * VP + ch * 32 + quad * 8];
                acc[0] = __builtin_amdgcn_mfma_f32_16x16x32_bf16(
                    __builtin_bit_cast(v8bf, af0), __builtin_bit_cast(v8bf, bfr), acc[0], 0, 0, 0);
                acc[1] = __builtin_amdgcn_mfma_f32_16x16x32_bf16(
                    __builtin_bit_cast(v8bf, af1), __builtin_bit_cast(v8bf, bfr), acc[1], 0, 0, 0);
            }
        }
    }

#pragma unroll
    for (int mt = 0; mt < 2; mt++) {
#pragma unroll
        for (int r = 0; r < 4; r++) {
            int och = mt * 16 + quad * 4 + r;
            if (och < 27)
                om[((size_t)b * 27 + och) * HWSZ + h * WW + wv * 16 + m16] =
                    acc[mt][r] + b_off[och];
        }
    }
}

// ---------------------------------------------------------------------------
// Main fused kernel. Block = (b,h) row, 512 thr (8 waves), tile 256o x 64px.
// Per kk: stage V_kk[64px][256ch] with COALESCED loads (lanes span channels,
// tap params broadcast wave-uniform from LDS), then 8 K-chunks of MFMA.
// ---------------------------------------------------------------------------
__global__ __launch_bounds__(512) void k_main(const unsigned short* __restrict__ x_t,
                                              const float* __restrict__ om,
                                              const unsigned short* __restrict__ wprep,
                                              float* __restrict__ out) {
    int id = blockIdx.x;
    int g  = id & 7, hi = (id >> 3) & 7, b = id >> 6;
    int h  = g * 8 + hi;
    int tid  = threadIdx.x;
    int lane = tid & 63;
    int oct  = tid >> 6;                   // wave 0..7: o in [oct*32, +32)
    int m16  = lane & 15;
    int quad = lane >> 4;

    __shared__ int4   s_base[KKT][64];     // 4 corner element-offsets
    __shared__ float4 s_wt  [KKT][64];     // bilinear*valid*mask weights
    __shared__ unsigned short s_v[64 * VP];

    // ---- Phase A: sampling params per (kk, px) ----
    const float* omb = om + (size_t)b * 27 * HWSZ + h * WW;
    for (int i = tid; i < KKT * 64; i += 512) {
        int kk = i >> 6;
        int p  = i & 63;
        float offy = omb[(size_t)(2 * kk)     * HWSZ + p];
        float offx = omb[(size_t)(2 * kk + 1) * HWSZ + p];
        float mv   = omb[(size_t)(18 + kk)    * HWSZ + p];
        int ky = kk / 3, kx = kk - 3 * (kk / 3);
        float py = (float)(h - 1 + ky) + offy;
        float px = (float)(p - 1 + kx) + offx;
        float y0f = floorf(py);
        float x0f = floorf(px);
        float ly = py - y0f, lx = px - x0f;
        int y0 = (int)y0f, x0 = (int)x0f;
        float m = 1.f / (1.f + __expf(-mv));
        bool yv0 = (unsigned)y0       < HH;
        bool yv1 = (unsigned)(y0 + 1) < HH;
        bool xv0 = (unsigned)x0       < WW;
        bool xv1 = (unsigned)(x0 + 1) < WW;
        int y0c = min(max(y0, 0), HH - 1);
        int y1c = min(max(y0 + 1, 0), HH - 1);
        int x0c = min(max(x0, 0), WW - 1);
        int x1c = min(max(x0 + 1, 0), WW - 1);
        s_base[kk][p] = make_int4((y0c * WW + x0c) * CIN, (y0c * WW + x1c) * CIN,
                                  (y1c * WW + x0c) * CIN, (y1c * WW + x1c) * CIN);
        s_wt[kk][p] = make_float4(
            (yv0 && xv0) ? (1.f - ly) * (1.f - lx) * m : 0.f,
            (yv0 && xv1) ? (1.f - ly) * lx         * m : 0.f,
            (yv1 && xv0) ? ly * (1.f - lx)         * m : 0.f,
            (yv1 && xv1) ? ly * lx                 * m : 0.f);
    }
    __syncthreads();

    v4f acc[2][4];
#pragma unroll
    for (int mt = 0; mt < 2; mt++)
#pragma unroll
        for (int nt = 0; nt < 4; nt++) acc[mt][nt] = (v4f)(0.f);

    const unsigned short* xb = x_t + (size_t)b * HWSZ * CIN;

    for (int kk = 0; kk < KKT; kk++) {
        // ---- stage V_kk: wave oct handles px = oct*8 .. +7; lanes = channels
#pragma unroll
        for (int i = 0; i < 8; i++) {
            int px = oct * 8 + i;
            int4   bp = s_base[kk][px];    // wave-uniform (LDS broadcast)
            float4 wt = s_wt[kk][px];
            const unsigned short* xc = xb + lane * 4;
            ushort4v t0 = *(const ushort4v*)(xc + bp.x);
            ushort4v t1 = *(const ushort4v*)(xc + bp.y);
            ushort4v t2 = *(const ushort4v*)(xc + bp.z);
            ushort4v t3 = *(const ushort4v*)(xc + bp.w);
            unsigned short vv[4];
#pragma unroll
            for (int j = 0; j < 4; j++) {
                float val = wt.x * bf2f(t0[j]) + wt.y * bf2f(t1[j])
                          + wt.z * bf2f(t2[j]) + wt.w * bf2f(t3[j]);
                vv[j] = f2bf(val);
            }
            *(ushort4v*)&s_v[px * VP + lane * 4] = *(ushort4v*)vv;
        }
        __syncthreads();

        // ---- 8 K-chunks of MFMA for this kk ----
#pragma unroll 2
        for (int ch = 0; ch < 8; ch++) {
            int t = kk * 8 + ch;
            const unsigned short* wp = wprep + ((size_t)t * 256 + oct * 32) * 32;
            short8 af0 = *(const short8*)(wp + m16 * 32 + quad * 8);
            short8 af1 = *(const short8*)(wp + (16 + m16) * 32 + quad * 8);
            short8 bfr[4];
#pragma unroll
            for (int nt = 0; nt < 4; nt++)
                bfr[nt] = *(const short8*)&s_v[(nt * 16 + m16) * VP + ch * 32 + quad * 8];
#pragma unroll
            for (int nt = 0; nt < 4; nt++) {
                acc[0][nt] = __builtin_amdgcn_mfma_f32_16x16x32_bf16(
                    __builtin_bit_cast(v8bf, af0), __builtin_bit_cast(v8bf, bfr[nt]),
                    acc[0][nt], 0, 0, 0);
                acc[1][nt] = __builtin_amdgcn_mfma_f32_16x16x32_bf16(
                    __builtin_bit_cast(v8bf, af1), __builtin_bit_cast(v8bf, bfr[nt]),
                    acc[1][nt], 0, 0, 0);
            }
        }
        __syncthreads();
    }

    // ---- epilogue ----
    float* ob = out + ((size_t)b * COUT) * HWSZ + h * WW;
#pragma unroll
    for (int mt = 0; mt < 2; mt++)
#pragma unroll
        for (int nt = 0; nt < 4; nt++)
#pragma unroll
            for (int r = 0; r < 4; r++) {
                int o = oct * 32 + mt * 16 + quad * 4 + r;
                ob[(size_t)o * HWSZ + nt * 16 + m16] = acc[mt][nt][r];
            }
}

extern "C" void kernel_launch(void* const* d_in, const int* in_sizes, int n_in,
                              void* d_out, int out_size, void* d_ws, size_t ws_size,
                              hipStream_t stream) {
    const float* x     = (const float*)d_in[0];
    const float* w_off = (const float*)d_in[1];
    const float* b_off = (const float*)d_in[2];
    const float* w     = (const float*)d_in[3];
    float* out = (float*)d_out;

    float* om = (float*)d_ws;                                // 442368 f32
    unsigned short* x_t   = (unsigned short*)(om + 442368);  // 4*4096*256 bf16
    unsigned short* wprep = x_t + (size_t)4 * HWSZ * CIN;    // 589824 bf16
    unsigned short* woffp = wprep + 589824;                  // 73728 bf16

    hipLaunchKernelGGL(k_prep_x,   dim3(256), dim3(256), 0, stream, x, x_t);
    hipLaunchKernelGGL(k_prep_wts, dim3(328), dim3(256), 0, stream, w, w_off, wprep, woffp);
    hipLaunchKernelGGL(k_off_mfma, dim3(256), dim3(256), 0, stream, x_t, woffp, b_off, om);
    hipLaunchKernelGGL(k_main,     dim3(256), dim3(512), 0, stream, x_t, om, wprep, out);
}